// Round 1
// baseline (107.108 us; speedup 1.0000x reference)
//
#include <hip/hip_runtime.h>

// T=256 frames, 20 boxes. Output (1, 5120, 5120) fp32 block-diagonal:
// diagonal block d holds iou(rois[d+1], rois[d+2]) for d in [0,254),
// block 255 holds iou(rois[0], rois[1]), block 254 is zero.
// Reference bug preserved: area_b uses b[...,2] in BOTH factors.
//
// Store-BW-bound: 104.9 MB written exactly once (~17 us at 6.3 TB/s).
// This version: 4 rows per 256-thread block (one wave64 per row), so each
// thread issues 20 unrolled float4 stores -> 4x the per-wave outstanding
// stores and 1/4 the workgroup count vs the previous 1-row-per-block shape
// (which measured ~2.5 TB/s effective store BW).

#define TT 256
#define NB 20
#define DIM (TT * NB)      // 5120 floats per row
#define DIM4 (DIM / 4)     // 1280 float4 per row
#define RPB 4              // rows per block; 4 | 20 so kr is block-uniform

__global__ void __launch_bounds__(256) fused_iou_diag_kernel(
        const float4* __restrict__ rois, float4* __restrict__ out) {
    const int wave = threadIdx.x >> 6;          // 0..3 -> which row of the 4
    const int lane = threadIdx.x & 63;
    const int row  = blockIdx.x * RPB + wave;   // 0..5119
    const int kr   = row / NB;                  // diagonal block index
    const int ri   = row - kr * NB;             // row within block

    const bool active = (kr != 254);
    const int t  = (kr == 255) ? 0 : kr + 1;    // a = rois[t], b = rois[t+1]
    const int tb = active ? t + 1 : 0;          // keep pointer math in-bounds

    const float4 a = rois[t * NB + ri];         // wave-broadcast load
    const float area_a = (a.z - a.x + 1.f) * (a.w - a.y + 1.f);

    const int bcol0 = kr * (NB / 4);            // first in-block float4 column
    const float4* brow = rois + tb * NB;
    float4* rowp = out + (size_t)row * DIM4;

    #pragma unroll
    for (int k = 0; k < DIM4 / 64; ++k) {       // 20 float4 stores per thread
        const int c4 = (k << 6) + lane;
        float4 v = make_float4(0.f, 0.f, 0.f, 0.f);
        const int j4 = c4 - bcol0;
        if (active && (unsigned)j4 < (unsigned)(NB / 4)) {
            float* vp = (float*)&v;
            #pragma unroll
            for (int q = 0; q < 4; ++q) {
                const float4 b = brow[j4 * 4 + q];
                const float ix1 = fmaxf(a.x, b.x);
                const float ix2 = fminf(a.z, b.z);
                const float iy1 = fmaxf(a.y, b.y);
                const float iy2 = fminf(a.w, b.w);
                const float inter =
                    fmaxf(ix2 - ix1, 0.f) * fmaxf(iy2 - iy1, 0.f);
                // reference bug preserved: b.z in both factors
                const float area_b = (b.z - b.x + 1.f) * (b.z - b.y + 1.f);
                vp[q] = inter / (area_a + area_b - inter);
            }
        }
        rowp[c4] = v;
    }
}

extern "C" void kernel_launch(void* const* d_in, const int* in_sizes, int n_in,
                              void* d_out, int out_size, void* d_ws, size_t ws_size,
                              hipStream_t stream) {
    const float4* rois = (const float4*)d_in[0];
    float4* out = (float4*)d_out;
    fused_iou_diag_kernel<<<DIM / RPB, 256, 0, stream>>>(rois, out);
}